// Round 7
// baseline (451.546 us; speedup 1.0000x reference)
//
#include <hip/hip_runtime.h>
#include <hip/hip_bf16.h>
#include <math.h>

typedef __hip_bfloat16 bf16;
typedef __attribute__((ext_vector_type(8))) short short8;
typedef __attribute__((ext_vector_type(4))) float floatx4;

#define D_MODEL 1024
#define NUM_HEADS 16
#define DK 64
#define SEQ 2048
#define BATCH 2
#define MROWS (BATCH * SEQ)          // 4096
#define KDIM 1024
#define SEG_X ((size_t)MROWS * D_MODEL)      // 4194304
#define SEG_W ((size_t)D_MODEL * D_MODEL)    // 1048576
#define QKSTRIDE 2048                         // fused Q|K row stride
#define ROPE_C (-9.2103403719761836f / 64.f)  // -ln(10000)/dk

__device__ inline void gload16(const void* g, void* l) {
    __builtin_amdgcn_global_load_lds(
        (const __attribute__((address_space(1))) void*)g,
        (__attribute__((address_space(3))) void*)l, 16, 0, 0);
}

// ---------------------------------------------------------------------------
// Cast fp32 inputs to bf16 workspace buffers.
// ---------------------------------------------------------------------------
__global__ __launch_bounds__(256) void cast_kernel(
    const float* __restrict__ x,  const float* __restrict__ Wq,
    const float* __restrict__ Wk, const float* __restrict__ Wv,
    const float* __restrict__ Wo,
    bf16* __restrict__ xb, bf16* __restrict__ w_all, bf16* __restrict__ wob)
{
    const size_t i = ((size_t)blockIdx.x * 256 + threadIdx.x) * 4;
    const float* src; bf16* dst;
    if (i < SEG_X)                    { src = x  + i;                       dst = xb + i; }
    else if (i < SEG_X + SEG_W)       { src = Wq + (i - SEG_X);             dst = w_all + (i - SEG_X); }
    else if (i < SEG_X + 2 * SEG_W)   { src = Wk + (i - SEG_X - SEG_W);     dst = w_all + (i - SEG_X); }
    else if (i < SEG_X + 3 * SEG_W)   { src = Wv + (i - SEG_X - 2 * SEG_W); dst = w_all + (i - SEG_X); }
    else                              { src = Wo + (i - SEG_X - 3 * SEG_W); dst = wob + (i - SEG_X - 3 * SEG_W); }
    float4 v = *reinterpret_cast<const float4*>(src);
    __hip_bfloat162 lo, hi;
    lo.x = __float2bfloat16(v.x); lo.y = __float2bfloat16(v.y);
    hi.x = __float2bfloat16(v.z); hi.y = __float2bfloat16(v.w);
    __hip_bfloat162* d2 = reinterpret_cast<__hip_bfloat162*>(dst);
    d2[0] = lo; d2[1] = hi;
}

// ---------------------------------------------------------------------------
// GEMM1: qkv-proj with fused RoPE (Q,K sections -> qkb, row stride 2048)
// and fused V transpose (V section -> vtb[bh][d][s], packed 8B stores).
// m97 structure: 128x128 tile, BK=32, mfma_f32_16x16x32_bf16.
// Logical N = 3072 (Q|K|V weight rows in w_all segments of 1024).
// ---------------------------------------------------------------------------
__global__ __launch_bounds__(256) void gemm1_kernel(
    const bf16* __restrict__ A, const bf16* __restrict__ W,
    bf16* __restrict__ qkb, bf16* __restrict__ vtb,
    const int* __restrict__ pos)
{
    __shared__ bf16 ldsA[128 * 32];
    __shared__ bf16 ldsB[128 * 32];

    const int tileM = blockIdx.x * 128;
    const int tileN = blockIdx.y * 128;
    const int t = threadIdx.x;
    const int w = t >> 6, j = t & 63;
    const int wm = (w & 1) * 64, wn = (w >> 1) * 64;
    const int l15 = j & 15, lq = j >> 4;

    const bf16* Bp = W + (size_t)tileN * KDIM;  // w_all is contiguous Wq|Wk|Wv

    floatx4 acc[4][4];
    #pragma unroll
    for (int a = 0; a < 4; ++a)
        #pragma unroll
        for (int b = 0; b < 4; ++b)
            acc[a][b] = (floatx4){0.f, 0.f, 0.f, 0.f};

    const int arow = j >> 2;
    const int acol = (j & 3) * 8;

    for (int kk = 0; kk < KDIM; kk += 32) {
        #pragma unroll
        for (int i = 0; i < 2; ++i) {
            const int rb = 32 * w + 16 * i;
            gload16(A  + (size_t)(tileM + rb + arow) * KDIM + kk + acol,
                    &ldsA[rb * 32]);
            gload16(Bp + (size_t)(rb + arow) * KDIM + kk + acol,
                    &ldsB[rb * 32]);
        }
        __syncthreads();

        short8 af[4], bfr[4];
        #pragma unroll
        for (int mt = 0; mt < 4; ++mt)
            af[mt] = *reinterpret_cast<const short8*>(
                &ldsA[(wm + mt * 16 + l15) * 32 + lq * 8]);
        #pragma unroll
        for (int nt = 0; nt < 4; ++nt)
            bfr[nt] = *reinterpret_cast<const short8*>(
                &ldsB[(wn + nt * 16 + l15) * 32 + lq * 8]);
        #pragma unroll
        for (int mt = 0; mt < 4; ++mt)
            #pragma unroll
            for (int nt = 0; nt < 4; ++nt)
                acc[mt][nt] = __builtin_amdgcn_mfma_f32_16x16x32_bf16(
                    af[mt], bfr[nt], acc[mt][nt], 0, 0, 0);
        __syncthreads();
    }

    // Epilogue. C/D layout: col = lane&15 (n), row = (lane>>4)*4 + reg (m).
    const int p64 = (pos[1] == 0);   // int64 little-endian positions?
    if (tileN < 2048) {
        // Q or K section: fused RoPE, write to qkb (row stride 2048).
        #pragma unroll
        for (int mt = 0; mt < 4; ++mt) {
            #pragma unroll
            for (int nt = 0; nt < 4; ++nt) {
                const int colg = tileN + wn + nt * 16 + l15;
                const int i = (colg & 63) >> 1;
                const float freq = __expf((float)(2 * i) * ROPE_C);
                #pragma unroll
                for (int r = 0; r < 4; ++r) {
                    const int row = tileM + wm + mt * 16 + lq * 4 + r;
                    const int s = row & (SEQ - 1);
                    const int ptok = p64 ? pos[2 * s] : pos[s];
                    const float v = acc[mt][nt][r];
                    const float pv = __shfl_xor(v, 1);
                    const float ang = (float)ptok * freq;
                    const float sn = sinf(ang), cs = cosf(ang);
                    const float outv = (colg & 1) ? fmaf(pv, sn, v * cs)
                                                  : (v * cs - pv * sn);
                    qkb[(size_t)row * QKSTRIDE + colg] = __float2bfloat16(outv);
                }
            }
        }
    } else {
        // V section: write transposed to vtb[bh][d][s] (packed 8B stores).
        const int bq = tileM >> 11;   // batch (uniform per block)
        #pragma unroll
        for (int mt = 0; mt < 4; ++mt) {
            const int s0 = (tileM & (SEQ - 1)) + wm + mt * 16 + lq * 4;
            #pragma unroll
            for (int nt = 0; nt < 4; ++nt) {
                const int colv = tileN - 2048 + wn + nt * 16 + l15;
                const int bh = bq * 16 + (colv >> 6);
                const int d = colv & 63;
                __hip_bfloat162 o2[2];
                o2[0].x = __float2bfloat16(acc[mt][nt][0]);
                o2[0].y = __float2bfloat16(acc[mt][nt][1]);
                o2[1].x = __float2bfloat16(acc[mt][nt][2]);
                o2[1].y = __float2bfloat16(acc[mt][nt][3]);
                *reinterpret_cast<uint2*>(
                    vtb + ((size_t)bh * 64 + d) * SEQ + s0) =
                    *reinterpret_cast<uint2*>(o2);
            }
        }
    }
}

// ---------------------------------------------------------------------------
// GEMM2 (output projection): C fp32 = A(bf16) @ B^T(bf16), N = 1024.
// ---------------------------------------------------------------------------
__global__ __launch_bounds__(256) void gemm2_kernel(
    const bf16* __restrict__ A, const bf16* __restrict__ B,
    float* __restrict__ C)
{
    __shared__ bf16 ldsA[128 * 32];
    __shared__ bf16 ldsB[128 * 32];

    const int tileM = blockIdx.x * 128;
    const int tileN = blockIdx.y * 128;
    const int t = threadIdx.x;
    const int w = t >> 6, j = t & 63;
    const int wm = (w & 1) * 64, wn = (w >> 1) * 64;
    const int l15 = j & 15, lq = j >> 4;

    floatx4 acc[4][4];
    #pragma unroll
    for (int a = 0; a < 4; ++a)
        #pragma unroll
        for (int b = 0; b < 4; ++b)
            acc[a][b] = (floatx4){0.f, 0.f, 0.f, 0.f};

    const int arow = j >> 2;
    const int acol = (j & 3) * 8;

    for (int kk = 0; kk < KDIM; kk += 32) {
        #pragma unroll
        for (int i = 0; i < 2; ++i) {
            const int rb = 32 * w + 16 * i;
            gload16(A + (size_t)(tileM + rb + arow) * KDIM + kk + acol,
                    &ldsA[rb * 32]);
            gload16(B + (size_t)(tileN + rb + arow) * KDIM + kk + acol,
                    &ldsB[rb * 32]);
        }
        __syncthreads();

        short8 af[4], bfr[4];
        #pragma unroll
        for (int mt = 0; mt < 4; ++mt)
            af[mt] = *reinterpret_cast<const short8*>(
                &ldsA[(wm + mt * 16 + l15) * 32 + lq * 8]);
        #pragma unroll
        for (int nt = 0; nt < 4; ++nt)
            bfr[nt] = *reinterpret_cast<const short8*>(
                &ldsB[(wn + nt * 16 + l15) * 32 + lq * 8]);
        #pragma unroll
        for (int mt = 0; mt < 4; ++mt)
            #pragma unroll
            for (int nt = 0; nt < 4; ++nt)
                acc[mt][nt] = __builtin_amdgcn_mfma_f32_16x16x32_bf16(
                    af[mt], bfr[nt], acc[mt][nt], 0, 0, 0);
        __syncthreads();
    }

    #pragma unroll
    for (int mt = 0; mt < 4; ++mt) {
        #pragma unroll
        for (int nt = 0; nt < 4; ++nt) {
            const int col = tileN + wn + nt * 16 + l15;
            #pragma unroll
            for (int r = 0; r < 4; ++r) {
                const int row = tileM + wm + mt * 16 + lq * 4 + r;
                C[(size_t)row * D_MODEL + col] = acc[mt][nt][r];
            }
        }
    }
}

// ---------------------------------------------------------------------------
// MFMA flash attention. Block = 4 waves = one (b,h) x 64-row Q tile.
// Q A-frags preloaded in registers; K and V^T staged via global_load_lds;
// Ps padded to 40 elems/row (16B-aligned, conflict-free).
// ---------------------------------------------------------------------------
__global__ __launch_bounds__(256) void flash_attn_kernel(
    const bf16* __restrict__ qk, const bf16* __restrict__ vtb,
    bf16* __restrict__ O)
{
    __shared__ bf16 Ks[2][64][32];
    __shared__ bf16 Vt[2][64][32];     // V^T panels: [kp][d][k%32]
    __shared__ bf16 Ps[4][2][16][40];  // per-wave P, padded rows

    const int qt = gridDim.x - 1 - blockIdx.x;   // heavy tiles first
    const int bh = blockIdx.y;
    const int b = bh >> 4, h = bh & 15;
    const int t = threadIdx.x;
    const int w = t >> 6, lane = t & 63;
    const int l15 = lane & 15, lq = lane >> 4;

    const bf16* qbase = qk + (size_t)b * SEQ * QKSTRIDE + h * 64;
    const bf16* kbase = qbase + 1024;
    const bf16* vbase = vtb + (size_t)bh * 64 * SEQ;

    // Preload Q A-fragments (row = l15 within wave's 16-row strip).
    short8 aq[2];
    {
        const bf16* qrow = qbase + (size_t)(qt * 64 + 16 * w + l15) * QKSTRIDE;
        aq[0] = *reinterpret_cast<const short8*>(qrow + lq * 8);
        aq[1] = *reinterpret_cast<const short8*>(qrow + 32 + lq * 8);
    }

    const int srow = lane >> 2;
    const int scol = (lane & 3) * 8;

    floatx4 accO[4];
    #pragma unroll
    for (int nt = 0; nt < 4; ++nt) accO[nt] = (floatx4){0.f, 0.f, 0.f, 0.f};
    float m_i[4], l_i[4];
    #pragma unroll
    for (int r = 0; r < 4; ++r) { m_i[r] = -1e30f; l_i[r] = 0.f; }

    for (int kt = 0; kt <= qt; ++kt) {
        #pragma unroll
        for (int p = 0; p < 2; ++p)
            gload16(kbase + (size_t)(kt * 64 + 16 * w + srow) * QKSTRIDE
                        + p * 32 + scol,
                    &Ks[p][16 * w][0]);
        #pragma unroll
        for (int p = 0; p < 2; ++p)
            gload16(vbase + (size_t)(16 * w + srow) * SEQ + kt * 64
                        + p * 32 + scol,
                    &Vt[p][16 * w][0]);
        __syncthreads();

        // ---- QK^T ----
        floatx4 accS[4];
        #pragma unroll
        for (int nt = 0; nt < 4; ++nt) accS[nt] = (floatx4){0.f, 0.f, 0.f, 0.f};
        #pragma unroll
        for (int p = 0; p < 2; ++p) {
            #pragma unroll
            for (int nt = 0; nt < 4; ++nt) {
                const short8 bk = *reinterpret_cast<const short8*>(
                    &Ks[p][nt * 16 + l15][lq * 8]);
                accS[nt] = __builtin_amdgcn_mfma_f32_16x16x32_bf16(
                    aq[p], bk, accS[nt], 0, 0, 0);
            }
        }

        // ---- scale + causal mask ----
        float sv[4][4];
        const int rowloc = 16 * w + lq * 4;
        const bool diag = (kt == qt);
        #pragma unroll
        for (int nt = 0; nt < 4; ++nt) {
            const int colloc = nt * 16 + l15;
            #pragma unroll
            for (int r = 0; r < 4; ++r) {
                float s = accS[nt][r] * 0.125f;
                if (diag && colloc > rowloc + r) s = -1e30f;
                sv[nt][r] = s;
            }
        }

        // ---- online softmax ----
        float rm[4], rs[4], alpha[4];
        #pragma unroll
        for (int r = 0; r < 4; ++r) {
            float v0 = fmaxf(fmaxf(sv[0][r], sv[1][r]), fmaxf(sv[2][r], sv[3][r]));
            v0 = fmaxf(v0, __shfl_xor(v0, 1));
            v0 = fmaxf(v0, __shfl_xor(v0, 2));
            v0 = fmaxf(v0, __shfl_xor(v0, 4));
            v0 = fmaxf(v0, __shfl_xor(v0, 8));
            const float mn = fmaxf(m_i[r], v0);
            alpha[r] = __expf(m_i[r] - mn);
            m_i[r] = mn;
            rm[r] = mn;
            rs[r] = 0.f;
        }
        #pragma unroll
        for (int nt = 0; nt < 4; ++nt) {
            #pragma unroll
            for (int r = 0; r < 4; ++r) {
                const float e = __expf(sv[nt][r] - rm[r]);
                const bf16 eb = __float2bfloat16(e);
                Ps[w][nt >> 1][lq * 4 + r][(nt & 1) * 16 + l15] = eb;
                rs[r] += __bfloat162float(eb);
            }
        }
        #pragma unroll
        for (int r = 0; r < 4; ++r) {
            float s0 = rs[r];
            s0 += __shfl_xor(s0, 1);
            s0 += __shfl_xor(s0, 2);
            s0 += __shfl_xor(s0, 4);
            s0 += __shfl_xor(s0, 8);
            l_i[r] = l_i[r] * alpha[r] + s0;
        }
        #pragma unroll
        for (int nt = 0; nt < 4; ++nt)
            #pragma unroll
            for (int r = 0; r < 4; ++r)
                accO[nt][r] *= alpha[r];

        // ---- PV ----
        #pragma unroll
        for (int kp = 0; kp < 2; ++kp) {
            const short8 ap = *reinterpret_cast<const short8*>(
                &Ps[w][kp][l15][lq * 8]);
            #pragma unroll
            for (int nt = 0; nt < 4; ++nt) {
                const short8 bv = *reinterpret_cast<const short8*>(
                    &Vt[kp][nt * 16 + l15][lq * 8]);
                accO[nt] = __builtin_amdgcn_mfma_f32_16x16x32_bf16(
                    ap, bv, accO[nt], 0, 0, 0);
            }
        }
        __syncthreads();
    }

    // ---- epilogue ----
    #pragma unroll
    for (int r = 0; r < 4; ++r) {
        const float inv = 1.f / l_i[r];
        const int qrow = qt * 64 + 16 * w + lq * 4 + r;
        #pragma unroll
        for (int nt = 0; nt < 4; ++nt) {
            O[((size_t)(b * SEQ + qrow)) * D_MODEL + h * DK + nt * 16 + l15] =
                __float2bfloat16(accO[nt][r] * inv);
        }
    }
}

extern "C" void kernel_launch(void* const* d_in, const int* in_sizes, int n_in,
                              void* d_out, int out_size, void* d_ws, size_t ws_size,
                              hipStream_t stream)
{
    const float* x   = (const float*)d_in[0];
    const int*   pos = (const int*)d_in[1];
    const float* Wq  = (const float*)d_in[2];
    const float* Wk  = (const float*)d_in[3];
    const float* Wv  = (const float*)d_in[4];
    const float* Wo  = (const float*)d_in[5];
    float* out = (float*)d_out;

    // ws (bf16): xb[4M] | w_all[3M] | wob[1M] | qkb[8M] | vtb[4M]  = 41.9 MB
    bf16* xb    = (bf16*)d_ws;
    bf16* w_all = xb + SEG_X;
    bf16* wob   = w_all + 3 * SEG_W;
    bf16* qkb   = wob + SEG_W;                     // 4096 x 2048 (Q|K roped)
    bf16* vtb   = qkb + (size_t)MROWS * QKSTRIDE;  // 32 bh x 64 d x 2048 s
    bf16* ob    = xb;                              // reuse: x dead after GEMM1

    cast_kernel<<<8192, 256, 0, stream>>>(x, Wq, Wk, Wv, Wo, xb, w_all, wob);
    gemm1_kernel<<<dim3(32, 24), 256, 0, stream>>>(xb, w_all, qkb, vtb, pos);
    flash_attn_kernel<<<dim3(32, 32), 256, 0, stream>>>(qkb, vtb, ob);
    gemm2_kernel<<<dim3(32, 8), 256, 0, stream>>>(ob, wob, out);
}

// Round 8
// 283.778 us; speedup vs baseline: 1.5912x; 1.5912x over previous
//
#include <hip/hip_runtime.h>
#include <hip/hip_bf16.h>
#include <math.h>

typedef __hip_bfloat16 bf16;
typedef __attribute__((ext_vector_type(8))) short short8;
typedef __attribute__((ext_vector_type(4))) float floatx4;

#define D_MODEL 1024
#define NUM_HEADS 16
#define DK 64
#define SEQ 2048
#define BATCH 2
#define MROWS (BATCH * SEQ)          // 4096
#define KDIM 1024
#define SEG_X ((size_t)MROWS * D_MODEL)      // 4194304
#define SEG_W ((size_t)D_MODEL * D_MODEL)    // 1048576
#define QKSTRIDE 2048                         // fused Q|K row stride
#define ROPE_C (-9.2103403719761836f / 64.f)  // -ln(10000)/dk

__device__ inline void gload16(const void* g, void* l) {
    __builtin_amdgcn_global_load_lds(
        (const __attribute__((address_space(1))) void*)g,
        (__attribute__((address_space(3))) void*)l, 16, 0, 0);
}

// ---------------------------------------------------------------------------
// Cast fp32 inputs to bf16 workspace buffers.
// ---------------------------------------------------------------------------
__global__ __launch_bounds__(256) void cast_kernel(
    const float* __restrict__ x,  const float* __restrict__ Wq,
    const float* __restrict__ Wk, const float* __restrict__ Wv,
    const float* __restrict__ Wo,
    bf16* __restrict__ xb, bf16* __restrict__ w_all, bf16* __restrict__ wob)
{
    const size_t i = ((size_t)blockIdx.x * 256 + threadIdx.x) * 4;
    const float* src; bf16* dst;
    if (i < SEG_X)                    { src = x  + i;                       dst = xb + i; }
    else if (i < SEG_X + SEG_W)       { src = Wq + (i - SEG_X);             dst = w_all + (i - SEG_X); }
    else if (i < SEG_X + 2 * SEG_W)   { src = Wk + (i - SEG_X - SEG_W);     dst = w_all + (i - SEG_X); }
    else if (i < SEG_X + 3 * SEG_W)   { src = Wv + (i - SEG_X - 2 * SEG_W); dst = w_all + (i - SEG_X); }
    else                              { src = Wo + (i - SEG_X - 3 * SEG_W); dst = wob + (i - SEG_X - 3 * SEG_W); }
    float4 v = *reinterpret_cast<const float4*>(src);
    __hip_bfloat162 lo, hi;
    lo.x = __float2bfloat16(v.x); lo.y = __float2bfloat16(v.y);
    hi.x = __float2bfloat16(v.z); hi.y = __float2bfloat16(v.w);
    __hip_bfloat162* d2 = reinterpret_cast<__hip_bfloat162*>(dst);
    d2[0] = lo; d2[1] = hi;
}

// ---------------------------------------------------------------------------
// GEMM1: qkv-proj. Q,K sections: fused RoPE (hardware __sinf/__cosf — NOT
// libm sinf, which spills around calls) -> qkb (row stride 2048).
// V section: MFMA operands SWAPPED (mfma(b,a) = transposed tile) so vtb gets
// written as [bh][d][s] with the same coalesced 16-lane x 32B pattern.
// ---------------------------------------------------------------------------
__global__ __launch_bounds__(256) void gemm1_kernel(
    const bf16* __restrict__ A, const bf16* __restrict__ W,
    bf16* __restrict__ qkb, bf16* __restrict__ vtb,
    const int* __restrict__ pos)
{
    __shared__ bf16 ldsA[128 * 32];
    __shared__ bf16 ldsB[128 * 32];

    const int tileM = blockIdx.x * 128;
    const int tileN = blockIdx.y * 128;
    const int t = threadIdx.x;
    const int w = t >> 6, j = t & 63;
    const int wm = (w & 1) * 64, wn = (w >> 1) * 64;
    const int l15 = j & 15, lq = j >> 4;
    const bool isV = (tileN >= 2048);

    const bf16* Bp = W + (size_t)tileN * KDIM;  // w_all contiguous Wq|Wk|Wv

    floatx4 acc[4][4];
    #pragma unroll
    for (int a = 0; a < 4; ++a)
        #pragma unroll
        for (int b = 0; b < 4; ++b)
            acc[a][b] = (floatx4){0.f, 0.f, 0.f, 0.f};

    const int arow = j >> 2;
    const int acol = (j & 3) * 8;

    for (int kk = 0; kk < KDIM; kk += 32) {
        #pragma unroll
        for (int i = 0; i < 2; ++i) {
            const int rb = 32 * w + 16 * i;
            gload16(A  + (size_t)(tileM + rb + arow) * KDIM + kk + acol,
                    &ldsA[rb * 32]);
            gload16(Bp + (size_t)(rb + arow) * KDIM + kk + acol,
                    &ldsB[rb * 32]);
        }
        __syncthreads();

        short8 af[4], bfr[4];
        #pragma unroll
        for (int mt = 0; mt < 4; ++mt)
            af[mt] = *reinterpret_cast<const short8*>(
                &ldsA[(wm + mt * 16 + l15) * 32 + lq * 8]);
        #pragma unroll
        for (int nt = 0; nt < 4; ++nt)
            bfr[nt] = *reinterpret_cast<const short8*>(
                &ldsB[(wn + nt * 16 + l15) * 32 + lq * 8]);
        if (isV) {
            // transposed: acc[mt][nt] = (W-tile rows) x (x-tile rows)^T
            #pragma unroll
            for (int mt = 0; mt < 4; ++mt)
                #pragma unroll
                for (int nt = 0; nt < 4; ++nt)
                    acc[mt][nt] = __builtin_amdgcn_mfma_f32_16x16x32_bf16(
                        bfr[nt], af[mt], acc[mt][nt], 0, 0, 0);
        } else {
            #pragma unroll
            for (int mt = 0; mt < 4; ++mt)
                #pragma unroll
                for (int nt = 0; nt < 4; ++nt)
                    acc[mt][nt] = __builtin_amdgcn_mfma_f32_16x16x32_bf16(
                        af[mt], bfr[nt], acc[mt][nt], 0, 0, 0);
        }
        __syncthreads();
    }

    const int p64 = (pos[1] == 0);   // int64 little-endian positions?
    if (!isV) {
        // Q/K: C/D layout col = lane&15 (n), row = lq*4+reg (m). Fused RoPE.
        #pragma unroll
        for (int mt = 0; mt < 4; ++mt) {
            #pragma unroll
            for (int nt = 0; nt < 4; ++nt) {
                const int colg = tileN + wn + nt * 16 + l15;
                const int i = (colg & 63) >> 1;
                const float freq = __expf((float)(2 * i) * ROPE_C);
                #pragma unroll
                for (int r = 0; r < 4; ++r) {
                    const int row = tileM + wm + mt * 16 + lq * 4 + r;
                    const int s = row & (SEQ - 1);
                    const int ptok = p64 ? pos[2 * s] : pos[s];
                    const float v = acc[mt][nt][r];
                    const float pv = __shfl_xor(v, 1);
                    const float ang = (float)ptok * freq;
                    const float sn = __sinf(ang), cs = __cosf(ang);
                    const float outv = (colg & 1) ? fmaf(pv, sn, v * cs)
                                                  : (v * cs - pv * sn);
                    qkb[(size_t)row * QKSTRIDE + colg] = __float2bfloat16(outv);
                }
            }
        }
    } else {
        // V (swapped operands): row dim = weight col (d), col dim = x row (s).
        const int bq = tileM >> 11;
        const int tileNoff = tileN - 2048;
        #pragma unroll
        for (int mt = 0; mt < 4; ++mt) {
            const int s = (tileM & (SEQ - 1)) + wm + mt * 16 + l15;
            #pragma unroll
            for (int nt = 0; nt < 4; ++nt) {
                #pragma unroll
                for (int r = 0; r < 4; ++r) {
                    const int vcol = tileNoff + wn + nt * 16 + lq * 4 + r;
                    const int bh = bq * 16 + (vcol >> 6);
                    const int d = vcol & 63;
                    vtb[((size_t)bh * 64 + d) * SEQ + s] =
                        __float2bfloat16(acc[mt][nt][r]);
                }
            }
        }
    }
}

// ---------------------------------------------------------------------------
// GEMM2 (output projection): C fp32 = A(bf16) @ B^T(bf16), N = 1024.
// ---------------------------------------------------------------------------
__global__ __launch_bounds__(256) void gemm2_kernel(
    const bf16* __restrict__ A, const bf16* __restrict__ B,
    float* __restrict__ C)
{
    __shared__ bf16 ldsA[128 * 32];
    __shared__ bf16 ldsB[128 * 32];

    const int tileM = blockIdx.x * 128;
    const int tileN = blockIdx.y * 128;
    const int t = threadIdx.x;
    const int w = t >> 6, j = t & 63;
    const int wm = (w & 1) * 64, wn = (w >> 1) * 64;
    const int l15 = j & 15, lq = j >> 4;

    floatx4 acc[4][4];
    #pragma unroll
    for (int a = 0; a < 4; ++a)
        #pragma unroll
        for (int b = 0; b < 4; ++b)
            acc[a][b] = (floatx4){0.f, 0.f, 0.f, 0.f};

    const int arow = j >> 2;
    const int acol = (j & 3) * 8;

    for (int kk = 0; kk < KDIM; kk += 32) {
        #pragma unroll
        for (int i = 0; i < 2; ++i) {
            const int rb = 32 * w + 16 * i;
            gload16(A + (size_t)(tileM + rb + arow) * KDIM + kk + acol,
                    &ldsA[rb * 32]);
            gload16(B + (size_t)(tileN + rb + arow) * KDIM + kk + acol,
                    &ldsB[rb * 32]);
        }
        __syncthreads();

        short8 af[4], bfr[4];
        #pragma unroll
        for (int mt = 0; mt < 4; ++mt)
            af[mt] = *reinterpret_cast<const short8*>(
                &ldsA[(wm + mt * 16 + l15) * 32 + lq * 8]);
        #pragma unroll
        for (int nt = 0; nt < 4; ++nt)
            bfr[nt] = *reinterpret_cast<const short8*>(
                &ldsB[(wn + nt * 16 + l15) * 32 + lq * 8]);
        #pragma unroll
        for (int mt = 0; mt < 4; ++mt)
            #pragma unroll
            for (int nt = 0; nt < 4; ++nt)
                acc[mt][nt] = __builtin_amdgcn_mfma_f32_16x16x32_bf16(
                    af[mt], bfr[nt], acc[mt][nt], 0, 0, 0);
        __syncthreads();
    }

    #pragma unroll
    for (int mt = 0; mt < 4; ++mt) {
        #pragma unroll
        for (int nt = 0; nt < 4; ++nt) {
            const int col = tileN + wn + nt * 16 + l15;
            #pragma unroll
            for (int r = 0; r < 4; ++r) {
                const int row = tileM + wm + mt * 16 + lq * 4 + r;
                C[(size_t)row * D_MODEL + col] = acc[mt][nt][r];
            }
        }
    }
}

// ---------------------------------------------------------------------------
// MFMA flash attention (round-7 structure: reg-resident Q frags, K and V^T
// staged via global_load_lds, Ps rows padded to 40).
// ---------------------------------------------------------------------------
__global__ __launch_bounds__(256) void flash_attn_kernel(
    const bf16* __restrict__ qk, const bf16* __restrict__ vtb,
    bf16* __restrict__ O)
{
    __shared__ bf16 Ks[2][64][32];
    __shared__ bf16 Vt[2][64][32];
    __shared__ bf16 Ps[4][2][16][40];

    const int qt = gridDim.x - 1 - blockIdx.x;
    const int bh = blockIdx.y;
    const int b = bh >> 4, h = bh & 15;
    const int t = threadIdx.x;
    const int w = t >> 6, lane = t & 63;
    const int l15 = lane & 15, lq = lane >> 4;

    const bf16* qbase = qk + (size_t)b * SEQ * QKSTRIDE + h * 64;
    const bf16* kbase = qbase + 1024;
    const bf16* vbase = vtb + (size_t)bh * 64 * SEQ;

    short8 aq[2];
    {
        const bf16* qrow = qbase + (size_t)(qt * 64 + 16 * w + l15) * QKSTRIDE;
        aq[0] = *reinterpret_cast<const short8*>(qrow + lq * 8);
        aq[1] = *reinterpret_cast<const short8*>(qrow + 32 + lq * 8);
    }

    const int srow = lane >> 2;
    const int scol = (lane & 3) * 8;

    floatx4 accO[4];
    #pragma unroll
    for (int nt = 0; nt < 4; ++nt) accO[nt] = (floatx4){0.f, 0.f, 0.f, 0.f};
    float m_i[4], l_i[4];
    #pragma unroll
    for (int r = 0; r < 4; ++r) { m_i[r] = -1e30f; l_i[r] = 0.f; }

    for (int kt = 0; kt <= qt; ++kt) {
        #pragma unroll
        for (int p = 0; p < 2; ++p)
            gload16(kbase + (size_t)(kt * 64 + 16 * w + srow) * QKSTRIDE
                        + p * 32 + scol,
                    &Ks[p][16 * w][0]);
        #pragma unroll
        for (int p = 0; p < 2; ++p)
            gload16(vbase + (size_t)(16 * w + srow) * SEQ + kt * 64
                        + p * 32 + scol,
                    &Vt[p][16 * w][0]);
        __syncthreads();

        floatx4 accS[4];
        #pragma unroll
        for (int nt = 0; nt < 4; ++nt) accS[nt] = (floatx4){0.f, 0.f, 0.f, 0.f};
        #pragma unroll
        for (int p = 0; p < 2; ++p) {
            #pragma unroll
            for (int nt = 0; nt < 4; ++nt) {
                const short8 bk = *reinterpret_cast<const short8*>(
                    &Ks[p][nt * 16 + l15][lq * 8]);
                accS[nt] = __builtin_amdgcn_mfma_f32_16x16x32_bf16(
                    aq[p], bk, accS[nt], 0, 0, 0);
            }
        }

        float sv[4][4];
        const int rowloc = 16 * w + lq * 4;
        const bool diag = (kt == qt);
        #pragma unroll
        for (int nt = 0; nt < 4; ++nt) {
            const int colloc = nt * 16 + l15;
            #pragma unroll
            for (int r = 0; r < 4; ++r) {
                float s = accS[nt][r] * 0.125f;
                if (diag && colloc > rowloc + r) s = -1e30f;
                sv[nt][r] = s;
            }
        }

        float rm[4], rs[4], alpha[4];
        #pragma unroll
        for (int r = 0; r < 4; ++r) {
            float v0 = fmaxf(fmaxf(sv[0][r], sv[1][r]), fmaxf(sv[2][r], sv[3][r]));
            v0 = fmaxf(v0, __shfl_xor(v0, 1));
            v0 = fmaxf(v0, __shfl_xor(v0, 2));
            v0 = fmaxf(v0, __shfl_xor(v0, 4));
            v0 = fmaxf(v0, __shfl_xor(v0, 8));
            const float mn = fmaxf(m_i[r], v0);
            alpha[r] = __expf(m_i[r] - mn);
            m_i[r] = mn;
            rm[r] = mn;
            rs[r] = 0.f;
        }
        #pragma unroll
        for (int nt = 0; nt < 4; ++nt) {
            #pragma unroll
            for (int r = 0; r < 4; ++r) {
                const float e = __expf(sv[nt][r] - rm[r]);
                const bf16 eb = __float2bfloat16(e);
                Ps[w][nt >> 1][lq * 4 + r][(nt & 1) * 16 + l15] = eb;
                rs[r] += __bfloat162float(eb);
            }
        }
        #pragma unroll
        for (int r = 0; r < 4; ++r) {
            float s0 = rs[r];
            s0 += __shfl_xor(s0, 1);
            s0 += __shfl_xor(s0, 2);
            s0 += __shfl_xor(s0, 4);
            s0 += __shfl_xor(s0, 8);
            l_i[r] = l_i[r] * alpha[r] + s0;
        }
        #pragma unroll
        for (int nt = 0; nt < 4; ++nt)
            #pragma unroll
            for (int r = 0; r < 4; ++r)
                accO[nt][r] *= alpha[r];

        #pragma unroll
        for (int kp = 0; kp < 2; ++kp) {
            const short8 ap = *reinterpret_cast<const short8*>(
                &Ps[w][kp][l15][lq * 8]);
            #pragma unroll
            for (int nt = 0; nt < 4; ++nt) {
                const short8 bv = *reinterpret_cast<const short8*>(
                    &Vt[kp][nt * 16 + l15][lq * 8]);
                accO[nt] = __builtin_amdgcn_mfma_f32_16x16x32_bf16(
                    ap, bv, accO[nt], 0, 0, 0);
            }
        }
        __syncthreads();
    }

    #pragma unroll
    for (int r = 0; r < 4; ++r) {
        const float inv = 1.f / l_i[r];
        const int qrow = qt * 64 + 16 * w + lq * 4 + r;
        #pragma unroll
        for (int nt = 0; nt < 4; ++nt) {
            O[((size_t)(b * SEQ + qrow)) * D_MODEL + h * DK + nt * 16 + l15] =
                __float2bfloat16(accO[nt][r] * inv);
        }
    }
}

extern "C" void kernel_launch(void* const* d_in, const int* in_sizes, int n_in,
                              void* d_out, int out_size, void* d_ws, size_t ws_size,
                              hipStream_t stream)
{
    const float* x   = (const float*)d_in[0];
    const int*   pos = (const int*)d_in[1];
    const float* Wq  = (const float*)d_in[2];
    const float* Wk  = (const float*)d_in[3];
    const float* Wv  = (const float*)d_in[4];
    const float* Wo  = (const float*)d_in[5];
    float* out = (float*)d_out;

    bf16* xb    = (bf16*)d_ws;
    bf16* w_all = xb + SEG_X;
    bf16* wob   = w_all + 3 * SEG_W;
    bf16* qkb   = wob + SEG_W;                     // 4096 x 2048 (Q|K roped)
    bf16* vtb   = qkb + (size_t)MROWS * QKSTRIDE;  // 32 bh x 64 d x 2048 s
    bf16* ob    = xb;                              // reuse: x dead after GEMM1

    cast_kernel<<<8192, 256, 0, stream>>>(x, Wq, Wk, Wv, Wo, xb, w_all, wob);
    gemm1_kernel<<<dim3(32, 24), 256, 0, stream>>>(xb, w_all, qkb, vtb, pos);
    flash_attn_kernel<<<dim3(32, 32), 256, 0, stream>>>(qkb, vtb, ob);
    gemm2_kernel<<<dim3(32, 8), 256, 0, stream>>>(ob, wob, out);
}

// Round 9
// 237.667 us; speedup vs baseline: 1.8999x; 1.1940x over previous
//
#include <hip/hip_runtime.h>
#include <hip/hip_bf16.h>
#include <math.h>

typedef __hip_bfloat16 bf16;
typedef __attribute__((ext_vector_type(8))) short short8;
typedef __attribute__((ext_vector_type(4))) float floatx4;

#define D_MODEL 1024
#define NUM_HEADS 16
#define DK 64
#define SEQ 2048
#define BATCH 2
#define MROWS (BATCH * SEQ)          // 4096
#define KDIM 1024
#define SEG_X ((size_t)MROWS * D_MODEL)      // 4194304
#define SEG_W ((size_t)D_MODEL * D_MODEL)    // 1048576
#define QKSTRIDE 2048                         // fused Q|K row stride
#define ROPE_C (-9.2103403719761836f / 64.f)  // -ln(10000)/dk

__device__ inline void gload16(const void* g, void* l) {
    __builtin_amdgcn_global_load_lds(
        (const __attribute__((address_space(1))) void*)g,
        (__attribute__((address_space(3))) void*)l, 16, 0, 0);
}

// ---------------------------------------------------------------------------
// Cast fp32 inputs to bf16 workspace buffers.
// ---------------------------------------------------------------------------
__global__ __launch_bounds__(256) void cast_kernel(
    const float* __restrict__ x,  const float* __restrict__ Wq,
    const float* __restrict__ Wk, const float* __restrict__ Wv,
    const float* __restrict__ Wo,
    bf16* __restrict__ xb, bf16* __restrict__ w_all, bf16* __restrict__ wob)
{
    const size_t i = ((size_t)blockIdx.x * 256 + threadIdx.x) * 4;
    const float* src; bf16* dst;
    if (i < SEG_X)                    { src = x  + i;                       dst = xb + i; }
    else if (i < SEG_X + SEG_W)       { src = Wq + (i - SEG_X);             dst = w_all + (i - SEG_X); }
    else if (i < SEG_X + 2 * SEG_W)   { src = Wk + (i - SEG_X - SEG_W);     dst = w_all + (i - SEG_X); }
    else if (i < SEG_X + 3 * SEG_W)   { src = Wv + (i - SEG_X - 2 * SEG_W); dst = w_all + (i - SEG_X); }
    else                              { src = Wo + (i - SEG_X - 3 * SEG_W); dst = wob + (i - SEG_X - 3 * SEG_W); }
    float4 v = *reinterpret_cast<const float4*>(src);
    __hip_bfloat162 lo, hi;
    lo.x = __float2bfloat16(v.x); lo.y = __float2bfloat16(v.y);
    hi.x = __float2bfloat16(v.z); hi.y = __float2bfloat16(v.w);
    __hip_bfloat162* d2 = reinterpret_cast<__hip_bfloat162*>(dst);
    d2[0] = lo; d2[1] = hi;
}

// ---------------------------------------------------------------------------
// GEMM1: qkv-proj. Q,K: fused RoPE (__sinf/__cosf hw intrinsics) -> qkb.
// V: swapped MFMA operands -> transposed tile -> coalesced vtb[bh][d][s].
// ---------------------------------------------------------------------------
__global__ __launch_bounds__(256) void gemm1_kernel(
    const bf16* __restrict__ A, const bf16* __restrict__ W,
    bf16* __restrict__ qkb, bf16* __restrict__ vtb,
    const int* __restrict__ pos)
{
    __shared__ bf16 ldsA[128 * 32];
    __shared__ bf16 ldsB[128 * 32];

    const int tileM = blockIdx.x * 128;
    const int tileN = blockIdx.y * 128;
    const int t = threadIdx.x;
    const int w = t >> 6, j = t & 63;
    const int wm = (w & 1) * 64, wn = (w >> 1) * 64;
    const int l15 = j & 15, lq = j >> 4;
    const bool isV = (tileN >= 2048);

    const bf16* Bp = W + (size_t)tileN * KDIM;

    floatx4 acc[4][4];
    #pragma unroll
    for (int a = 0; a < 4; ++a)
        #pragma unroll
        for (int b = 0; b < 4; ++b)
            acc[a][b] = (floatx4){0.f, 0.f, 0.f, 0.f};

    const int arow = j >> 2;
    const int acol = (j & 3) * 8;

    for (int kk = 0; kk < KDIM; kk += 32) {
        #pragma unroll
        for (int i = 0; i < 2; ++i) {
            const int rb = 32 * w + 16 * i;
            gload16(A  + (size_t)(tileM + rb + arow) * KDIM + kk + acol,
                    &ldsA[rb * 32]);
            gload16(Bp + (size_t)(rb + arow) * KDIM + kk + acol,
                    &ldsB[rb * 32]);
        }
        __syncthreads();

        short8 af[4], bfr[4];
        #pragma unroll
        for (int mt = 0; mt < 4; ++mt)
            af[mt] = *reinterpret_cast<const short8*>(
                &ldsA[(wm + mt * 16 + l15) * 32 + lq * 8]);
        #pragma unroll
        for (int nt = 0; nt < 4; ++nt)
            bfr[nt] = *reinterpret_cast<const short8*>(
                &ldsB[(wn + nt * 16 + l15) * 32 + lq * 8]);
        if (isV) {
            #pragma unroll
            for (int mt = 0; mt < 4; ++mt)
                #pragma unroll
                for (int nt = 0; nt < 4; ++nt)
                    acc[mt][nt] = __builtin_amdgcn_mfma_f32_16x16x32_bf16(
                        bfr[nt], af[mt], acc[mt][nt], 0, 0, 0);
        } else {
            #pragma unroll
            for (int mt = 0; mt < 4; ++mt)
                #pragma unroll
                for (int nt = 0; nt < 4; ++nt)
                    acc[mt][nt] = __builtin_amdgcn_mfma_f32_16x16x32_bf16(
                        af[mt], bfr[nt], acc[mt][nt], 0, 0, 0);
        }
        __syncthreads();
    }

    const int p64 = (pos[1] == 0);
    if (!isV) {
        #pragma unroll
        for (int mt = 0; mt < 4; ++mt) {
            #pragma unroll
            for (int nt = 0; nt < 4; ++nt) {
                const int colg = tileN + wn + nt * 16 + l15;
                const int i = (colg & 63) >> 1;
                const float freq = __expf((float)(2 * i) * ROPE_C);
                #pragma unroll
                for (int r = 0; r < 4; ++r) {
                    const int row = tileM + wm + mt * 16 + lq * 4 + r;
                    const int s = row & (SEQ - 1);
                    const int ptok = p64 ? pos[2 * s] : pos[s];
                    const float v = acc[mt][nt][r];
                    const float pv = __shfl_xor(v, 1);
                    const float ang = (float)ptok * freq;
                    const float sn = __sinf(ang), cs = __cosf(ang);
                    const float outv = (colg & 1) ? fmaf(pv, sn, v * cs)
                                                  : (v * cs - pv * sn);
                    qkb[(size_t)row * QKSTRIDE + colg] = __float2bfloat16(outv);
                }
            }
        }
    } else {
        const int bq = tileM >> 11;
        const int tileNoff = tileN - 2048;
        #pragma unroll
        for (int mt = 0; mt < 4; ++mt) {
            const int s = (tileM & (SEQ - 1)) + wm + mt * 16 + l15;
            #pragma unroll
            for (int nt = 0; nt < 4; ++nt) {
                #pragma unroll
                for (int r = 0; r < 4; ++r) {
                    const int vcol = tileNoff + wn + nt * 16 + lq * 4 + r;
                    const int bh = bq * 16 + (vcol >> 6);
                    const int d = vcol & 63;
                    vtb[((size_t)bh * 64 + d) * SEQ + s] =
                        __float2bfloat16(acc[mt][nt][r]);
                }
            }
        }
    }
}

// ---------------------------------------------------------------------------
// GEMM2 (output projection): C fp32 = A(bf16) @ B^T(bf16), N = 1024.
// ---------------------------------------------------------------------------
__global__ __launch_bounds__(256) void gemm2_kernel(
    const bf16* __restrict__ A, const bf16* __restrict__ B,
    float* __restrict__ C)
{
    __shared__ bf16 ldsA[128 * 32];
    __shared__ bf16 ldsB[128 * 32];

    const int tileM = blockIdx.x * 128;
    const int tileN = blockIdx.y * 128;
    const int t = threadIdx.x;
    const int w = t >> 6, j = t & 63;
    const int wm = (w & 1) * 64, wn = (w >> 1) * 64;
    const int l15 = j & 15, lq = j >> 4;

    floatx4 acc[4][4];
    #pragma unroll
    for (int a = 0; a < 4; ++a)
        #pragma unroll
        for (int b = 0; b < 4; ++b)
            acc[a][b] = (floatx4){0.f, 0.f, 0.f, 0.f};

    const int arow = j >> 2;
    const int acol = (j & 3) * 8;

    for (int kk = 0; kk < KDIM; kk += 32) {
        #pragma unroll
        for (int i = 0; i < 2; ++i) {
            const int rb = 32 * w + 16 * i;
            gload16(A + (size_t)(tileM + rb + arow) * KDIM + kk + acol,
                    &ldsA[rb * 32]);
            gload16(B + (size_t)(tileN + rb + arow) * KDIM + kk + acol,
                    &ldsB[rb * 32]);
        }
        __syncthreads();

        short8 af[4], bfr[4];
        #pragma unroll
        for (int mt = 0; mt < 4; ++mt)
            af[mt] = *reinterpret_cast<const short8*>(
                &ldsA[(wm + mt * 16 + l15) * 32 + lq * 8]);
        #pragma unroll
        for (int nt = 0; nt < 4; ++nt)
            bfr[nt] = *reinterpret_cast<const short8*>(
                &ldsB[(wn + nt * 16 + l15) * 32 + lq * 8]);
        #pragma unroll
        for (int mt = 0; mt < 4; ++mt)
            #pragma unroll
            for (int nt = 0; nt < 4; ++nt)
                acc[mt][nt] = __builtin_amdgcn_mfma_f32_16x16x32_bf16(
                    af[mt], bfr[nt], acc[mt][nt], 0, 0, 0);
        __syncthreads();
    }

    #pragma unroll
    for (int mt = 0; mt < 4; ++mt) {
        #pragma unroll
        for (int nt = 0; nt < 4; ++nt) {
            const int col = tileN + wn + nt * 16 + l15;
            #pragma unroll
            for (int r = 0; r < 4; ++r) {
                const int row = tileM + wm + mt * 16 + lq * 4 + r;
                C[(size_t)row * D_MODEL + col] = acc[mt][nt][r];
            }
        }
    }
}

// ---------------------------------------------------------------------------
// MFMA flash attention, paired q-tiles + double-buffered prefetch.
// Block = (qtA = bx, qtB = 31-bx) for one bh; wave w owns 16 rows of each.
// K/V tiles staged once per kt, shared by both q-tiles; K frags shared.
// Per-lane partial l (alpha-scaled), reduced once at the end.
// ---------------------------------------------------------------------------
__global__ __launch_bounds__(256) void flash_attn_kernel(
    const bf16* __restrict__ qk, const bf16* __restrict__ vtb,
    bf16* __restrict__ O)
{
    __shared__ bf16 Ks[2][2][64][32];      // [buf][panel][row][32]
    __shared__ bf16 Vt[2][2][64][32];
    __shared__ bf16 Ps[4][2][2][16][40];   // [wave][tile][kp][row][40]

    const int qtA = blockIdx.x;          // 0..15
    const int qtB = 31 - blockIdx.x;     // 31..16
    const int bh = blockIdx.y;
    const int b = bh >> 4, h = bh & 15;
    const int t = threadIdx.x;
    const int w = t >> 6, lane = t & 63;
    const int l15 = lane & 15, lq = lane >> 4;

    const bf16* qbase = qk + (size_t)b * SEQ * QKSTRIDE + h * 64;
    const bf16* kbase = qbase + 1024;
    const bf16* vbase = vtb + (size_t)bh * 64 * SEQ;

    // Preload Q A-fragments for both tiles.
    short8 aqA[2], aqB[2];
    {
        const bf16* qr = qbase + (size_t)(qtA * 64 + 16 * w + l15) * QKSTRIDE;
        aqA[0] = *reinterpret_cast<const short8*>(qr + lq * 8);
        aqA[1] = *reinterpret_cast<const short8*>(qr + 32 + lq * 8);
        qr = qbase + (size_t)(qtB * 64 + 16 * w + l15) * QKSTRIDE;
        aqB[0] = *reinterpret_cast<const short8*>(qr + lq * 8);
        aqB[1] = *reinterpret_cast<const short8*>(qr + 32 + lq * 8);
    }

    const int srow = lane >> 2;
    const int scol = (lane & 3) * 8;

    floatx4 accA[4], accB[4];
    float mA[4], lA[4], mB[4], lB[4];
    #pragma unroll
    for (int nt = 0; nt < 4; ++nt) {
        accA[nt] = (floatx4){0.f, 0.f, 0.f, 0.f};
        accB[nt] = (floatx4){0.f, 0.f, 0.f, 0.f};
    }
    #pragma unroll
    for (int r = 0; r < 4; ++r) {
        mA[r] = -1e30f; lA[r] = 0.f;
        mB[r] = -1e30f; lB[r] = 0.f;
    }

    const int rowloc = 16 * w + lq * 4;

    // softmax + PV for one tile (per-lane partial l, no in-loop sum reduce)
    auto softmax_pv = [&](floatx4* accS, floatx4* accO, float* m_i, float* l_i,
                          bool diag, int tslot, int cur) {
        float sv[4][4];
        #pragma unroll
        for (int nt = 0; nt < 4; ++nt) {
            const int colloc = nt * 16 + l15;
            #pragma unroll
            for (int r = 0; r < 4; ++r) {
                float s = accS[nt][r] * 0.125f;
                if (diag && colloc > rowloc + r) s = -1e30f;
                sv[nt][r] = s;
            }
        }
        float rm[4], alpha[4];
        #pragma unroll
        for (int r = 0; r < 4; ++r) {
            float v0 = fmaxf(fmaxf(sv[0][r], sv[1][r]), fmaxf(sv[2][r], sv[3][r]));
            v0 = fmaxf(v0, __shfl_xor(v0, 1));
            v0 = fmaxf(v0, __shfl_xor(v0, 2));
            v0 = fmaxf(v0, __shfl_xor(v0, 4));
            v0 = fmaxf(v0, __shfl_xor(v0, 8));
            const float mn = fmaxf(m_i[r], v0);
            alpha[r] = __expf(m_i[r] - mn);
            m_i[r] = mn;
            rm[r] = mn;
        }
        #pragma unroll
        for (int r = 0; r < 4; ++r) {
            float rs = 0.f;
            #pragma unroll
            for (int nt = 0; nt < 4; ++nt) {
                const float e = __expf(sv[nt][r] - rm[r]);
                const bf16 eb = __float2bfloat16(e);
                Ps[w][tslot][nt >> 1][lq * 4 + r][(nt & 1) * 16 + l15] = eb;
                rs += __bfloat162float(eb);
            }
            l_i[r] = l_i[r] * alpha[r] + rs;    // per-lane partial
        }
        #pragma unroll
        for (int nt = 0; nt < 4; ++nt)
            #pragma unroll
            for (int r = 0; r < 4; ++r)
                accO[nt][r] *= alpha[r];
        #pragma unroll
        for (int kp = 0; kp < 2; ++kp) {
            const short8 ap = *reinterpret_cast<const short8*>(
                &Ps[w][tslot][kp][l15][lq * 8]);
            #pragma unroll
            for (int nt = 0; nt < 4; ++nt) {
                const short8 bv = *reinterpret_cast<const short8*>(
                    &Vt[cur][kp][nt * 16 + l15][lq * 8]);
                accO[nt] = __builtin_amdgcn_mfma_f32_16x16x32_bf16(
                    ap, bv, accO[nt], 0, 0, 0);
            }
        }
    };

    auto stage = [&](int kt, int buf) {
        #pragma unroll
        for (int p = 0; p < 2; ++p) {
            gload16(kbase + (size_t)(kt * 64 + 16 * w + srow) * QKSTRIDE
                        + p * 32 + scol,
                    &Ks[buf][p][16 * w][0]);
            gload16(vbase + (size_t)(16 * w + srow) * SEQ + kt * 64
                        + p * 32 + scol,
                    &Vt[buf][p][16 * w][0]);
        }
    };

    stage(0, 0);
    __syncthreads();

    for (int kt = 0; kt <= qtB; ++kt) {
        const int cur = kt & 1, nxt = cur ^ 1;
        if (kt < qtB) stage(kt + 1, nxt);   // prefetch; drained by end barrier

        // K fragments (shared by both q-tiles)
        short8 bk[2][4];
        #pragma unroll
        for (int p = 0; p < 2; ++p)
            #pragma unroll
            for (int nt = 0; nt < 4; ++nt)
                bk[p][nt] = *reinterpret_cast<const short8*>(
                    &Ks[cur][p][nt * 16 + l15][lq * 8]);

        // QK^T for B (always) and A (if in range)
        floatx4 sB[4];
        #pragma unroll
        for (int nt = 0; nt < 4; ++nt) sB[nt] = (floatx4){0.f, 0.f, 0.f, 0.f};
        #pragma unroll
        for (int p = 0; p < 2; ++p)
            #pragma unroll
            for (int nt = 0; nt < 4; ++nt)
                sB[nt] = __builtin_amdgcn_mfma_f32_16x16x32_bf16(
                    aqB[p], bk[p][nt], sB[nt], 0, 0, 0);

        if (kt <= qtA) {
            floatx4 sA[4];
            #pragma unroll
            for (int nt = 0; nt < 4; ++nt) sA[nt] = (floatx4){0.f, 0.f, 0.f, 0.f};
            #pragma unroll
            for (int p = 0; p < 2; ++p)
                #pragma unroll
                for (int nt = 0; nt < 4; ++nt)
                    sA[nt] = __builtin_amdgcn_mfma_f32_16x16x32_bf16(
                        aqA[p], bk[p][nt], sA[nt], 0, 0, 0);
            softmax_pv(sB, accB, mB, lB, kt == qtB, 1, cur);
            softmax_pv(sA, accA, mA, lA, kt == qtA, 0, cur);
        } else {
            softmax_pv(sB, accB, mB, lB, kt == qtB, 1, cur);
        }
        __syncthreads();
    }

    // Final: reduce per-lane partial l across the 16 col-lanes, write O.
    auto epilogue = [&](floatx4* accO, float* l_i, int qt) {
        #pragma unroll
        for (int r = 0; r < 4; ++r) {
            float s0 = l_i[r];
            s0 += __shfl_xor(s0, 1);
            s0 += __shfl_xor(s0, 2);
            s0 += __shfl_xor(s0, 4);
            s0 += __shfl_xor(s0, 8);
            const float inv = 1.f / s0;
            const int qrow = qt * 64 + 16 * w + lq * 4 + r;
            #pragma unroll
            for (int nt = 0; nt < 4; ++nt) {
                O[((size_t)(b * SEQ + qrow)) * D_MODEL + h * DK + nt * 16 + l15] =
                    __float2bfloat16(accO[nt][r] * inv);
            }
        }
    };
    epilogue(accA, lA, qtA);
    epilogue(accB, lB, qtB);
}

extern "C" void kernel_launch(void* const* d_in, const int* in_sizes, int n_in,
                              void* d_out, int out_size, void* d_ws, size_t ws_size,
                              hipStream_t stream)
{
    const float* x   = (const float*)d_in[0];
    const int*   pos = (const int*)d_in[1];
    const float* Wq  = (const float*)d_in[2];
    const float* Wk  = (const float*)d_in[3];
    const float* Wv  = (const float*)d_in[4];
    const float* Wo  = (const float*)d_in[5];
    float* out = (float*)d_out;

    bf16* xb    = (bf16*)d_ws;
    bf16* w_all = xb + SEG_X;
    bf16* wob   = w_all + 3 * SEG_W;
    bf16* qkb   = wob + SEG_W;                     // 4096 x 2048 (Q|K roped)
    bf16* vtb   = qkb + (size_t)MROWS * QKSTRIDE;  // 32 bh x 64 d x 2048 s
    bf16* ob    = xb;                              // reuse: x dead after GEMM1

    cast_kernel<<<8192, 256, 0, stream>>>(x, Wq, Wk, Wv, Wo, xb, w_all, wob);
    gemm1_kernel<<<dim3(32, 24), 256, 0, stream>>>(xb, w_all, qkb, vtb, pos);
    flash_attn_kernel<<<dim3(16, 32), 256, 0, stream>>>(qkb, vtb, ob);
    gemm2_kernel<<<dim3(32, 8), 256, 0, stream>>>(ob, wob, out);
}